// Round 10
// baseline (227.131 us; speedup 1.0000x reference)
//
#include <hip/hip_runtime.h>

// FFTConv fused: y[b,d,:] = (h[d] (*) x[b,d])[0:L] + x[b,d]*B[d]
// d_model=1024, L=8192, batch=2, fp32. N=16384 = 16*16*16*4. One kernel,
// one 1024-thread block per channel.
// Pipeline: h-FFT (load-fused stage1 + 2 LDS stages) -> capture spectrum as
// PACKED BF16 in 16 VGPRs (4x uint4; (H+B)/N folded) -> x-FFT (same shape)
// -> register middle (fwd radix-4 w=1, cmul with unpacked H, inv radix-4)
// -> 2 inverse LDS stages -> final inverse stage fused with store.
// Register discipline (learned R1-R8): compiler pins this family at 64 VGPRs
// and spills above it. Peak live here = a[16](32) + Hpack(16) + temps < 64,
// the exact footprint R8's kernel B sustained without spill. bf16 H costs
// ~0 extra error (R8: absmax 2.0 = fp32 version).

#define L_SEQ   8192
#define N_FFT   16384
#define D_MODEL 1024
#define NTH     1024

// XOR swizzle on float2 index: bijective, stride-1 conflict-free, caps
// power-of-2-stride conflicts at ~4-way.
#define SWZ(i) ((i) ^ (((i) >> 4) & 15))

// W16 twiddle constants
#define C16_1 0.92387953251128675613f
#define S16_1 0.38268343236508977173f
#define C16_2 0.70710678118654752440f

__device__ __forceinline__ float2 cmul(float2 a, float2 b) {
    return make_float2(a.x * b.x - a.y * b.y, a.x * b.y + a.y * b.x);
}

// Hardware sin/cos of (2*pi*rev); exact-argument for rev = j * 2^-k.
__device__ __forceinline__ float2 hw_cis(float rev) {
    return make_float2(__builtin_amdgcn_cosf(rev), __builtin_amdgcn_sinf(rev));
}

// Pack two floats as bf16 (RNE) into one uint: re -> low half, im -> high.
__device__ __forceinline__ unsigned bf2pack(float re, float im) {
    unsigned br = __float_as_uint(re);
    br = (br + 0x7fffu + ((br >> 16) & 1u)) >> 16;
    unsigned bi = __float_as_uint(im);
    bi = (bi + 0x7fffu + ((bi >> 16) & 1u)) & 0xffff0000u;
    return br | bi;
}

__device__ __forceinline__ float2 bf2unpack(unsigned p) {
    return make_float2(__uint_as_float(p << 16), __uint_as_float(p & 0xffff0000u));
}

// Radix-4 butterfly, in place. S=-1 forward DFT, S=+1 inverse (unscaled).
template <int S>
__device__ __forceinline__ void bfly4(float2& r0, float2& r1, float2& r2, float2& r3) {
    const float2 t0 = make_float2(r0.x + r2.x, r0.y + r2.y);
    const float2 t1 = make_float2(r0.x - r2.x, r0.y - r2.y);
    const float2 t2 = make_float2(r1.x + r3.x, r1.y + r3.y);
    const float2 t3 = make_float2(r1.x - r3.x, r1.y - r3.y);
    r0 = make_float2(t0.x + t2.x, t0.y + t2.y);
    r2 = make_float2(t0.x - t2.x, t0.y - t2.y);
    if (S < 0) {
        r1 = make_float2(t1.x + t3.y, t1.y - t3.x);   // t1 - i*t3
        r3 = make_float2(t1.x - t3.y, t1.y + t3.x);   // t1 + i*t3
    } else {
        r1 = make_float2(t1.x - t3.y, t1.y + t3.x);
        r3 = make_float2(t1.x + t3.y, t1.y - t3.x);
    }
}

__device__ __forceinline__ float2 cmulc(float2 a, float re, float im) {
    return make_float2(a.x * re - a.y * im, a.x * im + a.y * re);
}

// W16^(m0*k1) twiddles between the two radix-4 levels of a DFT16 (slot m0+4k1).
template <int S>
__device__ __forceinline__ void dft16_mid_twiddle(float2 a[16]) {
    const float s = (float)S;
    a[5]  = cmulc(a[5],   C16_1,  s * S16_1);                   // e1
    a[9]  = cmulc(a[9],   C16_2,  s * C16_2);                   // e2
    a[13] = cmulc(a[13],  S16_1,  s * C16_1);                   // e3
    a[6]  = cmulc(a[6],   C16_2,  s * C16_2);                   // e2
    a[10] = make_float2(-s * a[10].y, s * a[10].x);             // e4 = S*i
    a[14] = cmulc(a[14], -C16_2,  s * C16_2);                   // e6
    a[7]  = cmulc(a[7],   S16_1,  s * C16_1);                   // e3
    a[11] = cmulc(a[11], -C16_2,  s * C16_2);                   // e6
    a[15] = cmulc(a[15], -C16_1, -s * S16_1);                   // e9
}

// In-register 16-point DFT. Input: logical m at slot m. Output: logical
// A[k1+4k2] at slot 4k1+k2 (digit-swapped). All indices compile-time.
template <int S>
__device__ __forceinline__ void dft16(float2 a[16]) {
    bfly4<S>(a[0], a[4], a[8],  a[12]);
    bfly4<S>(a[1], a[5], a[9],  a[13]);
    bfly4<S>(a[2], a[6], a[10], a[14]);
    bfly4<S>(a[3], a[7], a[11], a[15]);
    dft16_mid_twiddle<S>(a);
    bfly4<S>(a[0],  a[1],  a[2],  a[3]);
    bfly4<S>(a[4],  a[5],  a[6],  a[7]);
    bfly4<S>(a[8],  a[9],  a[10], a[11]);
    bfly4<S>(a[12], a[13], a[14], a[15]);
}

// Inner radix-4 level of DFT16 when inputs m1=2,3 are zero (padded signal):
// DFT4 of (p,q,0,0) -> X[k1] = p + q*W4^(S*k1), slot c+4k1.
template <int S>
__device__ __forceinline__ void inner4_halfzero(float2 a[16]) {
#pragma unroll
    for (int c = 0; c < 4; ++c) {
        const float2 p = a[c], q = a[c + 4];
        a[c]      = make_float2(p.x + q.x, p.y + q.y);
        a[c + 8]  = make_float2(p.x - q.x, p.y - q.y);
        if (S < 0) {
            a[c + 4]  = make_float2(p.x + q.y, p.y - q.x);   // p - i*q
            a[c + 12] = make_float2(p.x - q.y, p.y + q.x);   // p + i*q
        } else {
            a[c + 4]  = make_float2(p.x - q.y, p.y + q.x);
            a[c + 12] = make_float2(p.x + q.y, p.y - q.x);
        }
    }
}

// Shared tail of the fused forward load-stage: mid twiddle, outer bfly4,
// external twiddle chain W^(-j*L) (j = tid), digit-swapped scatter to LDS.
__device__ __forceinline__ void fwd_stage1_finish(float2* __restrict__ z,
                                                  const int tid, float2 a[16]) {
    dft16_mid_twiddle<-1>(a);
    bfly4<-1>(a[0],  a[1],  a[2],  a[3]);
    bfly4<-1>(a[4],  a[5],  a[6],  a[7]);
    bfly4<-1>(a[8],  a[9],  a[10], a[11]);
    bfly4<-1>(a[12], a[13], a[14], a[15]);
    const float2 w1 = hw_cis(-(float)tid * (1.0f / 16384.0f));
    z[SWZ(tid)] = a[0];
    float2 wc = w1;
#pragma unroll
    for (int L = 1; L < 16; ++L) {
        const int P = ((L & 3) << 2) | (L >> 2);   // slot of logical L
        z[SWZ(tid + (L << 10))] = cmul(a[P], wc);
        wc = cmul(wc, w1);
    }
    __syncthreads();
}

// One LDS radix-16 stage, span q = 1<<LQ (LQ = 6 or 2 here).
// S=-1: gather(m), DFT16, twiddle outputs W^(j*L), scatter(L).
// S=+1: gather(k), twiddle W^(j*k), DFT16, scatter(m). Exact stage inverse.
template <int S, int LQ>
__device__ __forceinline__ void fft16_stage(float2* __restrict__ z, const int tid) {
    const int q = 1 << LQ;
    const int j = tid & (q - 1);
    const int base = ((tid >> LQ) << (LQ + 4)) | j;
    const float2 w1 = hw_cis((float)S * (float)j / (float)(1 << (LQ + 4)));
    float2 a[16];
    if (S < 0) {
#pragma unroll
        for (int m = 0; m < 16; ++m) a[m] = z[SWZ(base + m * q)];
        dft16<S>(a);
        z[SWZ(base)] = a[0];
        float2 wc = w1;
#pragma unroll
        for (int L = 1; L < 16; ++L) {
            const int P = ((L & 3) << 2) | (L >> 2);
            z[SWZ(base + L * q)] = cmul(a[P], wc);
            wc = cmul(wc, w1);
        }
    } else {
#pragma unroll
        for (int k = 0; k < 16; ++k) a[k] = z[SWZ(base + k * q)];
        float2 wc = w1;
#pragma unroll
        for (int k = 1; k < 16; ++k) { a[k] = cmul(a[k], wc); wc = cmul(wc, w1); }
        dft16<S>(a);
#pragma unroll
        for (int M = 0; M < 16; ++M) {
            const int P = ((M & 3) << 2) | (M >> 2);
            z[SWZ(base + M * q)] = a[P];
        }
    }
    __syncthreads();
}

__global__ void __launch_bounds__(NTH) fftconv_fused_kernel(
        const float* __restrict__ h, const float* __restrict__ x,
        const float* __restrict__ Bg, float* __restrict__ y) {
    extern __shared__ float2 z[];
    const int d = blockIdx.x;
    const int tid = threadIdx.x;
    const float invn = 1.0f / (float)N_FFT;
    const float Bs = Bg[d] * invn;

    // ---- h-FFT: load-fused stage 1 (upper half zero) + 2 LDS stages ----
    {
        const float* hrow = h + (size_t)d * L_SEQ;
        float2 a[16];
#pragma unroll
        for (int m = 0; m < 8; ++m)
            a[m] = make_float2(hrow[tid + (m << 10)], 0.0f);
        inner4_halfzero<-1>(a);
        fwd_stage1_finish(z, tid, a);
    }
    fft16_stage<-1, 6>(z, tid);
    fft16_stage<-1, 2>(z, tid);

    // capture spectrum: final radix-4 (q=1, w=1) in regs -> packed bf16,
    // (H + B)/N folded. 16 VGPRs total.
    uint4 Hpack[4];
#pragma unroll
    for (int r = 0; r < 4; ++r) {
        const int b = 4 * (tid + r * NTH);
        float2 a0 = z[SWZ(b)], a1 = z[SWZ(b + 1)], a2 = z[SWZ(b + 2)], a3 = z[SWZ(b + 3)];
        bfly4<-1>(a0, a1, a2, a3);
        Hpack[r] = make_uint4(
            bf2pack(a0.x * invn + Bs, a0.y * invn),
            bf2pack(a1.x * invn + Bs, a1.y * invn),
            bf2pack(a2.x * invn + Bs, a2.y * invn),
            bf2pack(a3.x * invn + Bs, a3.y * invn));
    }
    __syncthreads();   // all reads of z done before x-phase overwrites

    // ---- x-FFT: load-fused stage 1 (z = x0 + i*x1) + 2 LDS stages ----
    const float* x0 = x + (size_t)d * L_SEQ;
    const float* x1 = x + (size_t)(D_MODEL + d) * L_SEQ;
    {
        float2 a[16];
#pragma unroll
        for (int m = 0; m < 8; ++m) {
            const int idx = tid + (m << 10);
            a[m] = make_float2(x0[idx], x1[idx]);
        }
        inner4_halfzero<-1>(a);
        fwd_stage1_finish(z, tid, a);
    }
    fft16_stage<-1, 6>(z, tid);
    fft16_stage<-1, 2>(z, tid);

    // ---- fused middle: fwd radix-4 (w=1) -> pointwise Hpack -> inv radix-4 ----
#pragma unroll
    for (int r = 0; r < 4; ++r) {
        const int b = 4 * (tid + r * NTH);
        const int p0 = SWZ(b), p1 = SWZ(b + 1), p2 = SWZ(b + 2), p3 = SWZ(b + 3);
        float2 a0 = z[p0], a1 = z[p1], a2 = z[p2], a3 = z[p3];
        bfly4<-1>(a0, a1, a2, a3);
        a0 = cmul(a0, bf2unpack(Hpack[r].x));
        a1 = cmul(a1, bf2unpack(Hpack[r].y));
        a2 = cmul(a2, bf2unpack(Hpack[r].z));
        a3 = cmul(a3, bf2unpack(Hpack[r].w));
        bfly4<+1>(a0, a1, a2, a3);
        z[p0] = a0; z[p1] = a1; z[p2] = a2; z[p3] = a3;
    }
    __syncthreads();

    // ---- inverse LDS stages ----
    fft16_stage<+1, 2>(z, tid);
    fft16_stage<+1, 6>(z, tid);

    // ---- final inverse stage (span 1024) fused with store of [0, 8192) ----
    {
        float2 a[16];
#pragma unroll
        for (int k = 0; k < 16; ++k) a[k] = z[SWZ(tid + (k << 10))];
        const float2 w1 = hw_cis((float)tid * (1.0f / 16384.0f));
        float2 wc = w1;
#pragma unroll
        for (int k = 1; k < 16; ++k) { a[k] = cmul(a[k], wc); wc = cmul(wc, w1); }
        bfly4<+1>(a[0], a[4], a[8],  a[12]);
        bfly4<+1>(a[1], a[5], a[9],  a[13]);
        bfly4<+1>(a[2], a[6], a[10], a[14]);
        bfly4<+1>(a[3], a[7], a[11], a[15]);
        dft16_mid_twiddle<+1>(a);
        float* y0 = y + (size_t)d * L_SEQ;
        float* y1 = y + (size_t)(D_MODEL + d) * L_SEQ;
        // outer bfly4, partial: only logical outputs M=g, g+4 (< 8192 kept)
#pragma unroll
        for (int g = 0; g < 4; ++g) {
            const float2 b0 = a[4*g], b1 = a[4*g+1], b2 = a[4*g+2], b3 = a[4*g+3];
            const float2 t0 = make_float2(b0.x + b2.x, b0.y + b2.y);
            const float2 t1 = make_float2(b0.x - b2.x, b0.y - b2.y);
            const float2 t2 = make_float2(b1.x + b3.x, b1.y + b3.y);
            const float2 t3 = make_float2(b1.x - b3.x, b1.y - b3.y);
            const float2 r0 = make_float2(t0.x + t2.x, t0.y + t2.y);   // M=g
            const float2 r1 = make_float2(t1.x - t3.y, t1.y + t3.x);   // M=g+4 (S=+1)
            const int q0 = tid + (g << 10);
            const int q1 = tid + ((g + 4) << 10);
            y0[q0] = r0.x; y1[q0] = r0.y;
            y0[q1] = r1.x; y1[q1] = r1.y;
        }
    }
}

extern "C" void kernel_launch(void* const* d_in, const int* in_sizes, int n_in,
                              void* d_out, int out_size, void* d_ws, size_t ws_size,
                              hipStream_t stream) {
    const float* h = (const float*)d_in[0];   // (1024, 8192)
    const float* x = (const float*)d_in[1];   // (2, 1024, 8192)
    const float* B = (const float*)d_in[2];   // (1024, 1)
    float* y = (float*)d_out;                 // (2, 1024, 8192)

    const size_t lds_bytes = (size_t)N_FFT * sizeof(float2);  // 128 KB

    fftconv_fused_kernel<<<dim3(D_MODEL), dim3(NTH), lds_bytes, stream>>>(h, x, B, y);
}

// Round 11
// 172.806 us; speedup vs baseline: 1.3144x; 1.3144x over previous
//
#include <hip/hip_runtime.h>

// FFTConv fused: y[b,d,:] = (h[d] (*) x[b,d])[0:L] + x[b,d]*B[d]
// d_model=1024, L=8192, batch=2, fp32. N=16384 = 16*16*16*4. ONE kernel,
// one 1024-thread block per channel.
// All intermediate storage is PACKED BF16 complex (one u32 = re.bf16|im.bf16):
//   zz[16384] (64KB): the signal buffer (h-FFT, then x-FFT / result)
//   Hu[16384] (64KB): the filter spectrum, SoA layout, (H+B)/N folded
// Total 128KB LDS, same footprint as the fp32 split version, but no HBM
// spectrum stream (R8 spent ~170MB on Hws write+fetch+writeback) and no
// second launch. Arithmetic is fp32 in registers; only LDS storage is bf16
// (bf16-H was measured error-free in R8: absmax 2.0 == fp32 version).
// Register discipline (R1-R9): compiler pins this family at 64 VGPRs and
// spills above -> phantom HBM writes. Peak live here = a[16]+temps ~ 45.
// Spill canary: WRITE_SIZE > ~90 MB. Accuracy canary: absmax > 8.88.

#define L_SEQ   8192
#define N_FFT   16384
#define D_MODEL 1024
#define NTH     1024

// XOR swizzle on u32 index: bijective, stride-1 conflict-free, spreads
// power-of-2 strides across banks.
#define SWZ(i) ((i) ^ (((i) >> 4) & 15))

// W16 twiddle constants
#define C16_1 0.92387953251128675613f
#define S16_1 0.38268343236508977173f
#define C16_2 0.70710678118654752440f

__device__ __forceinline__ float2 cmul(float2 a, float2 b) {
    return make_float2(a.x * b.x - a.y * b.y, a.x * b.y + a.y * b.x);
}

// Hardware sin/cos of (2*pi*rev); exact-argument for rev = j * 2^-k.
__device__ __forceinline__ float2 hw_cis(float rev) {
    return make_float2(__builtin_amdgcn_cosf(rev), __builtin_amdgcn_sinf(rev));
}

// Pack two floats as bf16 (RNE) into one uint: re -> low half, im -> high.
__device__ __forceinline__ unsigned bf2pack(float re, float im) {
    unsigned br = __float_as_uint(re);
    br = (br + 0x7fffu + ((br >> 16) & 1u)) >> 16;
    unsigned bi = __float_as_uint(im);
    bi = (bi + 0x7fffu + ((bi >> 16) & 1u)) & 0xffff0000u;
    return br | bi;
}

__device__ __forceinline__ unsigned bf2pack2(float2 v) { return bf2pack(v.x, v.y); }

__device__ __forceinline__ float2 bf2unpack(unsigned p) {
    return make_float2(__uint_as_float(p << 16), __uint_as_float(p & 0xffff0000u));
}

// Radix-4 butterfly, in place. S=-1 forward DFT, S=+1 inverse (unscaled).
template <int S>
__device__ __forceinline__ void bfly4(float2& r0, float2& r1, float2& r2, float2& r3) {
    const float2 t0 = make_float2(r0.x + r2.x, r0.y + r2.y);
    const float2 t1 = make_float2(r0.x - r2.x, r0.y - r2.y);
    const float2 t2 = make_float2(r1.x + r3.x, r1.y + r3.y);
    const float2 t3 = make_float2(r1.x - r3.x, r1.y - r3.y);
    r0 = make_float2(t0.x + t2.x, t0.y + t2.y);
    r2 = make_float2(t0.x - t2.x, t0.y - t2.y);
    if (S < 0) {
        r1 = make_float2(t1.x + t3.y, t1.y - t3.x);   // t1 - i*t3
        r3 = make_float2(t1.x - t3.y, t1.y + t3.x);   // t1 + i*t3
    } else {
        r1 = make_float2(t1.x - t3.y, t1.y + t3.x);
        r3 = make_float2(t1.x + t3.y, t1.y - t3.x);
    }
}

__device__ __forceinline__ float2 cmulc(float2 a, float re, float im) {
    return make_float2(a.x * re - a.y * im, a.x * im + a.y * re);
}

// W16^(m0*k1) twiddles between the two radix-4 levels of a DFT16 (slot m0+4k1).
template <int S>
__device__ __forceinline__ void dft16_mid_twiddle(float2 a[16]) {
    const float s = (float)S;
    a[5]  = cmulc(a[5],   C16_1,  s * S16_1);                   // e1
    a[9]  = cmulc(a[9],   C16_2,  s * C16_2);                   // e2
    a[13] = cmulc(a[13],  S16_1,  s * C16_1);                   // e3
    a[6]  = cmulc(a[6],   C16_2,  s * C16_2);                   // e2
    a[10] = make_float2(-s * a[10].y, s * a[10].x);             // e4 = S*i
    a[14] = cmulc(a[14], -C16_2,  s * C16_2);                   // e6
    a[7]  = cmulc(a[7],   S16_1,  s * C16_1);                   // e3
    a[11] = cmulc(a[11], -C16_2,  s * C16_2);                   // e6
    a[15] = cmulc(a[15], -C16_1, -s * S16_1);                   // e9
}

// In-register 16-point DFT. Input: logical m at slot m. Output: logical
// A[k1+4k2] at slot 4k1+k2 (digit-swapped). All indices compile-time.
template <int S>
__device__ __forceinline__ void dft16(float2 a[16]) {
    bfly4<S>(a[0], a[4], a[8],  a[12]);
    bfly4<S>(a[1], a[5], a[9],  a[13]);
    bfly4<S>(a[2], a[6], a[10], a[14]);
    bfly4<S>(a[3], a[7], a[11], a[15]);
    dft16_mid_twiddle<S>(a);
    bfly4<S>(a[0],  a[1],  a[2],  a[3]);
    bfly4<S>(a[4],  a[5],  a[6],  a[7]);
    bfly4<S>(a[8],  a[9],  a[10], a[11]);
    bfly4<S>(a[12], a[13], a[14], a[15]);
}

// Inner radix-4 level of DFT16 when inputs m1=2,3 are zero (padded signal):
// DFT4 of (p,q,0,0) -> X[k1] = p + q*W4^(S*k1), slot c+4k1.
template <int S>
__device__ __forceinline__ void inner4_halfzero(float2 a[16]) {
#pragma unroll
    for (int c = 0; c < 4; ++c) {
        const float2 p = a[c], q = a[c + 4];
        a[c]      = make_float2(p.x + q.x, p.y + q.y);
        a[c + 8]  = make_float2(p.x - q.x, p.y - q.y);
        if (S < 0) {
            a[c + 4]  = make_float2(p.x + q.y, p.y - q.x);   // p - i*q
            a[c + 12] = make_float2(p.x - q.y, p.y + q.x);   // p + i*q
        } else {
            a[c + 4]  = make_float2(p.x - q.y, p.y + q.x);
            a[c + 12] = make_float2(p.x + q.y, p.y - q.x);
        }
    }
}

// Shared tail of the fused forward load-stage: mid twiddle, outer bfly4,
// external twiddle chain W^(-j*L) (j = tid), digit-swapped scatter to zz.
__device__ __forceinline__ void fwd_stage1_finish(unsigned* __restrict__ zz,
                                                  const int tid, float2 a[16]) {
    dft16_mid_twiddle<-1>(a);
    bfly4<-1>(a[0],  a[1],  a[2],  a[3]);
    bfly4<-1>(a[4],  a[5],  a[6],  a[7]);
    bfly4<-1>(a[8],  a[9],  a[10], a[11]);
    bfly4<-1>(a[12], a[13], a[14], a[15]);
    const float2 w1 = hw_cis(-(float)tid * (1.0f / 16384.0f));
    zz[SWZ(tid)] = bf2pack2(a[0]);
    float2 wc = w1;
#pragma unroll
    for (int L = 1; L < 16; ++L) {
        const int P = ((L & 3) << 2) | (L >> 2);   // slot of logical L
        zz[SWZ(tid + (L << 10))] = bf2pack2(cmul(a[P], wc));
        wc = cmul(wc, w1);
    }
    __syncthreads();
}

// One LDS radix-16 stage on the packed-bf16 buffer, span q = 1<<LQ (6 or 2).
// S=-1: gather(m), DFT16, twiddle outputs W^(j*L), scatter(L).
// S=+1: gather(k), twiddle W^(j*k), DFT16, scatter(m). Exact stage inverse.
template <int S, int LQ>
__device__ __forceinline__ void fft16_stage_bf(unsigned* __restrict__ zz, const int tid) {
    const int q = 1 << LQ;
    const int j = tid & (q - 1);
    const int base = ((tid >> LQ) << (LQ + 4)) | j;
    const float2 w1 = hw_cis((float)S * (float)j / (float)(1 << (LQ + 4)));
    float2 a[16];
    if (S < 0) {
#pragma unroll
        for (int m = 0; m < 16; ++m) a[m] = bf2unpack(zz[SWZ(base + m * q)]);
        dft16<S>(a);
        zz[SWZ(base)] = bf2pack2(a[0]);
        float2 wc = w1;
#pragma unroll
        for (int L = 1; L < 16; ++L) {
            const int P = ((L & 3) << 2) | (L >> 2);
            zz[SWZ(base + L * q)] = bf2pack2(cmul(a[P], wc));
            wc = cmul(wc, w1);
        }
    } else {
#pragma unroll
        for (int k = 0; k < 16; ++k) a[k] = bf2unpack(zz[SWZ(base + k * q)]);
        float2 wc = w1;
#pragma unroll
        for (int k = 1; k < 16; ++k) { a[k] = cmul(a[k], wc); wc = cmul(wc, w1); }
        dft16<S>(a);
#pragma unroll
        for (int M = 0; M < 16; ++M) {
            const int P = ((M & 3) << 2) | (M >> 2);
            zz[SWZ(base + M * q)] = bf2pack2(a[P]);
        }
    }
    __syncthreads();
}

__global__ void __launch_bounds__(NTH) fftconv_fused_kernel(
        const float* __restrict__ h, const float* __restrict__ x,
        const float* __restrict__ Bg, float* __restrict__ y) {
    extern __shared__ unsigned lds[];
    unsigned* zz = lds;            // [16384] packed bf16 signal, SWZ-indexed
    unsigned* Hu = lds + N_FFT;    // [16384] packed bf16 spectrum, SoA layout
    const int d = blockIdx.x;
    const int tid = threadIdx.x;
    const float invn = 1.0f / (float)N_FFT;
    const float Bs = Bg[d] * invn;

    // ---- h-FFT: load-fused stage 1 (upper half zero) + 2 LDS stages ----
    {
        const float* hrow = h + (size_t)d * L_SEQ;
        float2 a[16];
#pragma unroll
        for (int m = 0; m < 8; ++m)
            a[m] = make_float2(hrow[tid + (m << 10)], 0.0f);
        inner4_halfzero<-1>(a);
        fwd_stage1_finish(zz, tid, a);
    }
    fft16_stage_bf<-1, 6>(zz, tid);
    fft16_stage_bf<-1, 2>(zz, tid);

    // capture spectrum: final radix-4 (q=1, w=1) in regs -> Hu (SoA: bin 4i+j
    // at Hu[j*4096+i], stride-1 conflict-free), (H + B)/N folded.
#pragma unroll
    for (int r = 0; r < 4; ++r) {
        const int i = tid + r * NTH;
        const int b = 4 * i;
        float2 a0 = bf2unpack(zz[SWZ(b)]);
        float2 a1 = bf2unpack(zz[SWZ(b + 1)]);
        float2 a2 = bf2unpack(zz[SWZ(b + 2)]);
        float2 a3 = bf2unpack(zz[SWZ(b + 3)]);
        bfly4<-1>(a0, a1, a2, a3);
        Hu[i]            = bf2pack(a0.x * invn + Bs, a0.y * invn);
        Hu[i + 4096]     = bf2pack(a1.x * invn + Bs, a1.y * invn);
        Hu[i + 2 * 4096] = bf2pack(a2.x * invn + Bs, a2.y * invn);
        Hu[i + 3 * 4096] = bf2pack(a3.x * invn + Bs, a3.y * invn);
    }
    __syncthreads();   // zz reads done before x-phase overwrites

    // ---- x-FFT: load-fused stage 1 (z = x0 + i*x1) + 2 LDS stages ----
    const float* x0 = x + (size_t)d * L_SEQ;
    const float* x1 = x + (size_t)(D_MODEL + d) * L_SEQ;
    {
        float2 a[16];
#pragma unroll
        for (int m = 0; m < 8; ++m) {
            const int idx = tid + (m << 10);
            a[m] = make_float2(x0[idx], x1[idx]);
        }
        inner4_halfzero<-1>(a);
        fwd_stage1_finish(zz, tid, a);
    }
    fft16_stage_bf<-1, 6>(zz, tid);
    fft16_stage_bf<-1, 2>(zz, tid);

    // ---- fused middle: fwd radix-4 (w=1) -> pointwise Hu -> inv radix-4 ----
#pragma unroll
    for (int r = 0; r < 4; ++r) {
        const int i = tid + r * NTH;
        const int b = 4 * i;
        const int p0 = SWZ(b), p1 = SWZ(b + 1), p2 = SWZ(b + 2), p3 = SWZ(b + 3);
        float2 a0 = bf2unpack(zz[p0]);
        float2 a1 = bf2unpack(zz[p1]);
        float2 a2 = bf2unpack(zz[p2]);
        float2 a3 = bf2unpack(zz[p3]);
        bfly4<-1>(a0, a1, a2, a3);
        a0 = cmul(a0, bf2unpack(Hu[i]));
        a1 = cmul(a1, bf2unpack(Hu[i + 4096]));
        a2 = cmul(a2, bf2unpack(Hu[i + 2 * 4096]));
        a3 = cmul(a3, bf2unpack(Hu[i + 3 * 4096]));
        bfly4<+1>(a0, a1, a2, a3);
        zz[p0] = bf2pack2(a0);
        zz[p1] = bf2pack2(a1);
        zz[p2] = bf2pack2(a2);
        zz[p3] = bf2pack2(a3);
    }
    __syncthreads();

    // ---- inverse LDS stages ----
    fft16_stage_bf<+1, 2>(zz, tid);
    fft16_stage_bf<+1, 6>(zz, tid);

    // ---- final inverse stage (span 1024) fused with store of [0, 8192) ----
    {
        float2 a[16];
#pragma unroll
        for (int k = 0; k < 16; ++k) a[k] = bf2unpack(zz[SWZ(tid + (k << 10))]);
        const float2 w1 = hw_cis((float)tid * (1.0f / 16384.0f));
        float2 wc = w1;
#pragma unroll
        for (int k = 1; k < 16; ++k) { a[k] = cmul(a[k], wc); wc = cmul(wc, w1); }
        bfly4<+1>(a[0], a[4], a[8],  a[12]);
        bfly4<+1>(a[1], a[5], a[9],  a[13]);
        bfly4<+1>(a[2], a[6], a[10], a[14]);
        bfly4<+1>(a[3], a[7], a[11], a[15]);
        dft16_mid_twiddle<+1>(a);
        float* y0 = y + (size_t)d * L_SEQ;
        float* y1 = y + (size_t)(D_MODEL + d) * L_SEQ;
        // outer bfly4, partial: only logical outputs M=g, g+4 (< 8192 kept)
#pragma unroll
        for (int g = 0; g < 4; ++g) {
            const float2 b0 = a[4*g], b1 = a[4*g+1], b2 = a[4*g+2], b3 = a[4*g+3];
            const float2 t0 = make_float2(b0.x + b2.x, b0.y + b2.y);
            const float2 t1 = make_float2(b0.x - b2.x, b0.y - b2.y);
            const float2 t2 = make_float2(b1.x + b3.x, b1.y + b3.y);
            const float2 t3 = make_float2(b1.x - b3.x, b1.y - b3.y);
            const float2 r0 = make_float2(t0.x + t2.x, t0.y + t2.y);   // M=g
            const float2 r1 = make_float2(t1.x - t3.y, t1.y + t3.x);   // M=g+4 (S=+1)
            const int q0 = tid + (g << 10);
            const int q1 = tid + ((g + 4) << 10);
            y0[q0] = r0.x; y1[q0] = r0.y;
            y0[q1] = r1.x; y1[q1] = r1.y;
        }
    }
}

extern "C" void kernel_launch(void* const* d_in, const int* in_sizes, int n_in,
                              void* d_out, int out_size, void* d_ws, size_t ws_size,
                              hipStream_t stream) {
    const float* h = (const float*)d_in[0];   // (1024, 8192)
    const float* x = (const float*)d_in[1];   // (2, 1024, 8192)
    const float* B = (const float*)d_in[2];   // (1024, 1)
    float* y = (float*)d_out;                 // (2, 1024, 8192)

    const size_t lds_bytes = (size_t)(2 * N_FFT) * sizeof(unsigned);  // 128 KB

    fftconv_fused_kernel<<<dim3(D_MODEL), dim3(NTH), lds_bytes, stream>>>(h, x, B, y);
}

// Round 12
// 104.281 us; speedup vs baseline: 2.1781x; 1.6571x over previous
//
#include <hip/hip_runtime.h>

// FFTConv: y[b,d,:] = (h[d] (*) x[b,d])[0:L] + x[b,d]*B[d]
// d_model=1024, L=8192, batch=2, fp32. N=16384 = 16*16*16*4.
// TWO kernels (R9/R10 lesson: fusing both FFT phases into one kernel always
// re-spills past the immovable 64-VGPR cap; each half runs clean).
// R11: signal buffer zz is PACKED BF16 complex (u32 = re.bf16|im.bf16) ->
// LDS = 64 KB -> 2 blocks/CU (was 1 at 128 KB fp32): doubles the latency-
// hiding pool and halves LDS traffic. bf16 storage measured accuracy-free
// (R8/R10: absmax 2.0, identical to fp32). Arithmetic stays fp32 in regs.
//   A: Hws[d] = digit-rev spectrum( (FFT(pad(h[d])) + B[d]) / N ), bf16 pairs
//   B: y = stage-exact-inverse( FFT(pad(x0+i*x1)) .* Hws ), natural order

#define L_SEQ   8192
#define N_FFT   16384
#define D_MODEL 1024
#define NTH     1024

// XOR swizzle on u32 index: bijective, stride-1 conflict-free, spreads
// power-of-2 strides across banks.
#define SWZ(i) ((i) ^ (((i) >> 4) & 15))

// W16 twiddle constants
#define C16_1 0.92387953251128675613f
#define S16_1 0.38268343236508977173f
#define C16_2 0.70710678118654752440f

__device__ __forceinline__ float2 cmul(float2 a, float2 b) {
    return make_float2(a.x * b.x - a.y * b.y, a.x * b.y + a.y * b.x);
}

// Hardware sin/cos of (2*pi*rev); exact-argument for rev = j * 2^-k.
__device__ __forceinline__ float2 hw_cis(float rev) {
    return make_float2(__builtin_amdgcn_cosf(rev), __builtin_amdgcn_sinf(rev));
}

// Pack two floats as bf16 (RNE) into one uint: re -> low half, im -> high.
__device__ __forceinline__ unsigned bf2pack(float re, float im) {
    unsigned br = __float_as_uint(re);
    br = (br + 0x7fffu + ((br >> 16) & 1u)) >> 16;
    unsigned bi = __float_as_uint(im);
    bi = (bi + 0x7fffu + ((bi >> 16) & 1u)) & 0xffff0000u;
    return br | bi;
}

__device__ __forceinline__ unsigned bf2pack2(float2 v) { return bf2pack(v.x, v.y); }

__device__ __forceinline__ float2 bf2unpack(unsigned p) {
    return make_float2(__uint_as_float(p << 16), __uint_as_float(p & 0xffff0000u));
}

// Radix-4 butterfly, in place. S=-1 forward DFT, S=+1 inverse (unscaled).
template <int S>
__device__ __forceinline__ void bfly4(float2& r0, float2& r1, float2& r2, float2& r3) {
    const float2 t0 = make_float2(r0.x + r2.x, r0.y + r2.y);
    const float2 t1 = make_float2(r0.x - r2.x, r0.y - r2.y);
    const float2 t2 = make_float2(r1.x + r3.x, r1.y + r3.y);
    const float2 t3 = make_float2(r1.x - r3.x, r1.y - r3.y);
    r0 = make_float2(t0.x + t2.x, t0.y + t2.y);
    r2 = make_float2(t0.x - t2.x, t0.y - t2.y);
    if (S < 0) {
        r1 = make_float2(t1.x + t3.y, t1.y - t3.x);   // t1 - i*t3
        r3 = make_float2(t1.x - t3.y, t1.y + t3.x);   // t1 + i*t3
    } else {
        r1 = make_float2(t1.x - t3.y, t1.y + t3.x);
        r3 = make_float2(t1.x + t3.y, t1.y - t3.x);
    }
}

__device__ __forceinline__ float2 cmulc(float2 a, float re, float im) {
    return make_float2(a.x * re - a.y * im, a.x * im + a.y * re);
}

// W16^(m0*k1) twiddles between the two radix-4 levels of a DFT16 (slot m0+4k1).
template <int S>
__device__ __forceinline__ void dft16_mid_twiddle(float2 a[16]) {
    const float s = (float)S;
    a[5]  = cmulc(a[5],   C16_1,  s * S16_1);                   // e1
    a[9]  = cmulc(a[9],   C16_2,  s * C16_2);                   // e2
    a[13] = cmulc(a[13],  S16_1,  s * C16_1);                   // e3
    a[6]  = cmulc(a[6],   C16_2,  s * C16_2);                   // e2
    a[10] = make_float2(-s * a[10].y, s * a[10].x);             // e4 = S*i
    a[14] = cmulc(a[14], -C16_2,  s * C16_2);                   // e6
    a[7]  = cmulc(a[7],   S16_1,  s * C16_1);                   // e3
    a[11] = cmulc(a[11], -C16_2,  s * C16_2);                   // e6
    a[15] = cmulc(a[15], -C16_1, -s * S16_1);                   // e9
}

// In-register 16-point DFT. Input: logical m at slot m. Output: logical
// A[k1+4k2] at slot 4k1+k2 (digit-swapped). All indices compile-time.
template <int S>
__device__ __forceinline__ void dft16(float2 a[16]) {
    bfly4<S>(a[0], a[4], a[8],  a[12]);
    bfly4<S>(a[1], a[5], a[9],  a[13]);
    bfly4<S>(a[2], a[6], a[10], a[14]);
    bfly4<S>(a[3], a[7], a[11], a[15]);
    dft16_mid_twiddle<S>(a);
    bfly4<S>(a[0],  a[1],  a[2],  a[3]);
    bfly4<S>(a[4],  a[5],  a[6],  a[7]);
    bfly4<S>(a[8],  a[9],  a[10], a[11]);
    bfly4<S>(a[12], a[13], a[14], a[15]);
}

// Inner radix-4 level of DFT16 when inputs m1=2,3 are zero (padded signal):
// DFT4 of (p,q,0,0) -> X[k1] = p + q*W4^(S*k1), slot c+4k1.
template <int S>
__device__ __forceinline__ void inner4_halfzero(float2 a[16]) {
#pragma unroll
    for (int c = 0; c < 4; ++c) {
        const float2 p = a[c], q = a[c + 4];
        a[c]      = make_float2(p.x + q.x, p.y + q.y);
        a[c + 8]  = make_float2(p.x - q.x, p.y - q.y);
        if (S < 0) {
            a[c + 4]  = make_float2(p.x + q.y, p.y - q.x);   // p - i*q
            a[c + 12] = make_float2(p.x - q.y, p.y + q.x);   // p + i*q
        } else {
            a[c + 4]  = make_float2(p.x - q.y, p.y + q.x);
            a[c + 12] = make_float2(p.x + q.y, p.y - q.x);
        }
    }
}

// Shared tail of the fused forward load-stage: mid twiddle, outer bfly4,
// external twiddle chain W^(-j*L) (j = tid), digit-swapped scatter to zz.
__device__ __forceinline__ void fwd_stage1_finish(unsigned* __restrict__ zz,
                                                  const int tid, float2 a[16]) {
    dft16_mid_twiddle<-1>(a);
    bfly4<-1>(a[0],  a[1],  a[2],  a[3]);
    bfly4<-1>(a[4],  a[5],  a[6],  a[7]);
    bfly4<-1>(a[8],  a[9],  a[10], a[11]);
    bfly4<-1>(a[12], a[13], a[14], a[15]);
    const float2 w1 = hw_cis(-(float)tid * (1.0f / 16384.0f));
    zz[SWZ(tid)] = bf2pack2(a[0]);
    float2 wc = w1;
#pragma unroll
    for (int L = 1; L < 16; ++L) {
        const int P = ((L & 3) << 2) | (L >> 2);   // slot of logical L
        zz[SWZ(tid + (L << 10))] = bf2pack2(cmul(a[P], wc));
        wc = cmul(wc, w1);
    }
    __syncthreads();
}

// One LDS radix-16 stage on the packed-bf16 buffer, span q = 1<<LQ (6 or 2).
// S=-1: gather(m), DFT16, twiddle outputs W^(j*L), scatter(L).
// S=+1: gather(k), twiddle W^(j*k), DFT16, scatter(m). Exact stage inverse.
template <int S, int LQ>
__device__ __forceinline__ void fft16_stage_bf(unsigned* __restrict__ zz, const int tid) {
    const int q = 1 << LQ;
    const int j = tid & (q - 1);
    const int base = ((tid >> LQ) << (LQ + 4)) | j;
    const float2 w1 = hw_cis((float)S * (float)j / (float)(1 << (LQ + 4)));
    float2 a[16];
    if (S < 0) {
#pragma unroll
        for (int m = 0; m < 16; ++m) a[m] = bf2unpack(zz[SWZ(base + m * q)]);
        dft16<S>(a);
        zz[SWZ(base)] = bf2pack2(a[0]);
        float2 wc = w1;
#pragma unroll
        for (int L = 1; L < 16; ++L) {
            const int P = ((L & 3) << 2) | (L >> 2);
            zz[SWZ(base + L * q)] = bf2pack2(cmul(a[P], wc));
            wc = cmul(wc, w1);
        }
    } else {
#pragma unroll
        for (int k = 0; k < 16; ++k) a[k] = bf2unpack(zz[SWZ(base + k * q)]);
        float2 wc = w1;
#pragma unroll
        for (int k = 1; k < 16; ++k) { a[k] = cmul(a[k], wc); wc = cmul(wc, w1); }
        dft16<S>(a);
#pragma unroll
        for (int M = 0; M < 16; ++M) {
            const int P = ((M & 3) << 2) | (M >> 2);
            zz[SWZ(base + M * q)] = bf2pack2(a[P]);
        }
    }
    __syncthreads();
}

// Kernel A: filter spectrum -> Hws (packed bf16), digit-reversed order,
// (H + B)/N folded before quantization. LDS 64 KB -> 2 blocks/CU.
__global__ void __launch_bounds__(NTH) fftconv_filter_kernel(
        const float* __restrict__ h, const float* __restrict__ Bg,
        unsigned* __restrict__ Hws) {
    extern __shared__ unsigned zz[];
    const int d = blockIdx.x;
    const int tid = threadIdx.x;
    const float invn = 1.0f / (float)N_FFT;
    const float Bs = Bg[d] * invn;

    // fused: load h (upper half zero) + forward stage 1 (span 1024)
    {
        const float* hrow = h + (size_t)d * L_SEQ;
        float2 a[16];
#pragma unroll
        for (int m = 0; m < 8; ++m)
            a[m] = make_float2(hrow[tid + (m << 10)], 0.0f);
        inner4_halfzero<-1>(a);
        fwd_stage1_finish(zz, tid, a);
    }
    fft16_stage_bf<-1, 6>(zz, tid);
    fft16_stage_bf<-1, 2>(zz, tid);

    // final forward stage (radix-4, q=1, w==1) in regs; stream out coalesced
    unsigned* Hrow = Hws + (size_t)d * N_FFT;
#pragma unroll
    for (int r = 0; r < 4; ++r) {
        const int i = tid + r * NTH;
        const int b = 4 * i;
        float2 a0 = bf2unpack(zz[SWZ(b)]);
        float2 a1 = bf2unpack(zz[SWZ(b + 1)]);
        float2 a2 = bf2unpack(zz[SWZ(b + 2)]);
        float2 a3 = bf2unpack(zz[SWZ(b + 3)]);
        bfly4<-1>(a0, a1, a2, a3);
        ((uint4*)(Hrow + b))[0] = make_uint4(
            bf2pack(a0.x * invn + Bs, a0.y * invn),
            bf2pack(a1.x * invn + Bs, a1.y * invn),
            bf2pack(a2.x * invn + Bs, a2.y * invn),
            bf2pack(a3.x * invn + Bs, a3.y * invn));
    }
}

// Kernel B: y = inverse( FFT(x0 + i*x1) .* Hws ), natural-order output.
// LDS 64 KB -> 2 blocks/CU.
__global__ void __launch_bounds__(NTH) fftconv_conv_kernel(
        const float* __restrict__ x, const unsigned* __restrict__ Hws,
        float* __restrict__ y) {
    extern __shared__ unsigned zz[];
    const int d = blockIdx.x;
    const int tid = threadIdx.x;

    const float* x0 = x + (size_t)d * L_SEQ;
    const float* x1 = x + (size_t)(D_MODEL + d) * L_SEQ;

    // fused: load x0+i*x1 (upper half zero) + forward stage 1 (span 1024)
    {
        float2 a[16];
#pragma unroll
        for (int m = 0; m < 8; ++m) {
            const int idx = tid + (m << 10);
            a[m] = make_float2(x0[idx], x1[idx]);
        }
        inner4_halfzero<-1>(a);
        fwd_stage1_finish(zz, tid, a);
    }
    fft16_stage_bf<-1, 6>(zz, tid);

    // prefetch this thread's 16 H bins (4x uint4 = 16 VGPRs) one stage early;
    // vmcnt stays outstanding across the next stage's barrier.
    const uint4* Hp = (const uint4*)(Hws + (size_t)d * N_FFT);
    const uint4 hp0 = Hp[tid];
    const uint4 hp1 = Hp[tid + NTH];
    const uint4 hp2 = Hp[tid + 2 * NTH];
    const uint4 hp3 = Hp[tid + 3 * NTH];

    fft16_stage_bf<-1, 2>(zz, tid);

    // fused middle: fwd radix-4 (w=1) -> pointwise Hws -> inv radix-4 (w=1)
#pragma unroll
    for (int r = 0; r < 4; ++r) {
        const int b = 4 * (tid + r * NTH);
        const int p0 = SWZ(b), p1 = SWZ(b + 1), p2 = SWZ(b + 2), p3 = SWZ(b + 3);
        float2 a0 = bf2unpack(zz[p0]);
        float2 a1 = bf2unpack(zz[p1]);
        float2 a2 = bf2unpack(zz[p2]);
        float2 a3 = bf2unpack(zz[p3]);
        bfly4<-1>(a0, a1, a2, a3);
        const uint4 hp = (r == 0) ? hp0 : (r == 1) ? hp1 : (r == 2) ? hp2 : hp3;
        a0 = cmul(a0, bf2unpack(hp.x));
        a1 = cmul(a1, bf2unpack(hp.y));
        a2 = cmul(a2, bf2unpack(hp.z));
        a3 = cmul(a3, bf2unpack(hp.w));
        bfly4<+1>(a0, a1, a2, a3);
        zz[p0] = bf2pack2(a0);
        zz[p1] = bf2pack2(a1);
        zz[p2] = bf2pack2(a2);
        zz[p3] = bf2pack2(a3);
    }
    __syncthreads();

    fft16_stage_bf<+1, 2>(zz, tid);
    fft16_stage_bf<+1, 6>(zz, tid);

    // fused: final inverse stage (span 1024) + store of outputs [0, 8192)
    {
        float2 a[16];
#pragma unroll
        for (int k = 0; k < 16; ++k) a[k] = bf2unpack(zz[SWZ(tid + (k << 10))]);
        const float2 w1 = hw_cis((float)tid * (1.0f / 16384.0f));
        float2 wc = w1;
#pragma unroll
        for (int k = 1; k < 16; ++k) { a[k] = cmul(a[k], wc); wc = cmul(wc, w1); }
        bfly4<+1>(a[0], a[4], a[8],  a[12]);
        bfly4<+1>(a[1], a[5], a[9],  a[13]);
        bfly4<+1>(a[2], a[6], a[10], a[14]);
        bfly4<+1>(a[3], a[7], a[11], a[15]);
        dft16_mid_twiddle<+1>(a);
        float* y0 = y + (size_t)d * L_SEQ;
        float* y1 = y + (size_t)(D_MODEL + d) * L_SEQ;
        // outer bfly4, partial: only logical outputs M=g, g+4 (< 8192 kept)
#pragma unroll
        for (int g = 0; g < 4; ++g) {
            const float2 b0 = a[4*g], b1 = a[4*g+1], b2 = a[4*g+2], b3 = a[4*g+3];
            const float2 t0 = make_float2(b0.x + b2.x, b0.y + b2.y);
            const float2 t1 = make_float2(b0.x - b2.x, b0.y - b2.y);
            const float2 t2 = make_float2(b1.x + b3.x, b1.y + b3.y);
            const float2 t3 = make_float2(b1.x - b3.x, b1.y - b3.y);
            const float2 r0 = make_float2(t0.x + t2.x, t0.y + t2.y);   // M=g
            const float2 r1 = make_float2(t1.x - t3.y, t1.y + t3.x);   // M=g+4 (S=+1)
            const int q0 = tid + (g << 10);
            const int q1 = tid + ((g + 4) << 10);
            y0[q0] = r0.x; y1[q0] = r0.y;
            y0[q1] = r1.x; y1[q1] = r1.y;
        }
    }
}

extern "C" void kernel_launch(void* const* d_in, const int* in_sizes, int n_in,
                              void* d_out, int out_size, void* d_ws, size_t ws_size,
                              hipStream_t stream) {
    const float* h = (const float*)d_in[0];   // (1024, 8192)
    const float* x = (const float*)d_in[1];   // (2, 1024, 8192)
    const float* B = (const float*)d_in[2];   // (1024, 1)
    float* y = (float*)d_out;                 // (2, 1024, 8192)
    unsigned* Hws = (unsigned*)d_ws;          // 1024 x 16384 packed bf16 = 67 MB

    const size_t lds_bytes = (size_t)N_FFT * sizeof(unsigned);  // 64 KB

    fftconv_filter_kernel<<<dim3(D_MODEL), dim3(NTH), lds_bytes, stream>>>(h, B, Hws);
    fftconv_conv_kernel<<<dim3(D_MODEL), dim3(NTH), lds_bytes, stream>>>(x, Hws, y);
}